// Round 10
// baseline (140.837 us; speedup 1.0000x reference)
//
#include <hip/hip_runtime.h>
#include <hip/hip_fp16.h>
#include <math.h>

#define DET 512
#define NA 180
#define NTILES 2048                   // 32 (x) x 64 (y) tiles of 16x8 pixels
#define TANG_FLOATS (NTILES * NA * 4) // 5.9 MB
#define CHUNK 18
#define WWIN 20
#define NITEM (CHUNK * WWIN * 2)      // 720 uint4 per chunk
#define NPF 6                         // ceil(720/128)

typedef _Float16 half2_t __attribute__((ext_vector_type(2)));

// ws layout (floats):
//  [0, TANG_FLOATS)  : tang float4 per (tile,angle): {bias=255.5-w0, C, S, w0 int bits}
//  then xsT2         : uint4[NA*DET*2] tap-pair-packed sinogram (2.95 MB):
//                      uint4 (a,d,g) = { half2(s_b[d], s_b[d+1]) : b = 4g..4g+3 }

// ---------------- fused prep + filter ----------------
// blocks [0, 2*NA): filter (angle = blk>>1, batch-half z = blk&1, 4 batches)
// blocks [2*NA, 2*NA+1440): prep of tang
__global__ __launch_bounds__(256) void prep_filter_kernel(const float* __restrict__ x,
                                                          float4* __restrict__ tang,
                                                          uint4* __restrict__ xsT2) {
    const int t = threadIdx.x;
    if (blockIdx.x >= 2 * NA) {
        int idx = (blockIdx.x - 2 * NA) * 256 + t;
        if (idx < NTILES * NA) {
            int tile = idx / NA;
            int a = idx - tile * NA;
            float th = (float)a * 0.017453292519943295f;
            float C = 255.5f * cosf(th);
            float S = 255.5f * sinf(th);
            int x0 = (tile & 31) << 4, y0 = (tile >> 5) << 3;
            float xga = (float)(2 * x0 - 511)        * (1.0f / 511.0f);
            float xgb = (float)(2 * (x0 + 15) - 511) * (1.0f / 511.0f);
            float yga = (float)(2 * y0 - 511)        * (1.0f / 511.0f);
            float ygb = (float)(2 * (y0 + 7) - 511)  * (1.0f / 511.0f);
            // min over tile corners of yv = 255.5 + xg*C - yg*S (linear in xg,yg)
            float mn = 255.5f + fminf(xga * C, xgb * C) + fminf(-yga * S, -ygb * S);
            int w0 = (int)floorf(mn) - 1;     // -1 slack for fma rounding differences
            tang[idx] = make_float4(255.5f - (float)w0, C, S, __int_as_float(w0));
        }
        return;
    }

    // ---- filter: one wave = full 512-tap conv of one batch-column ----
    __shared__ float xcols[4][DET];   // 8 KB
    __shared__ float g2s[1024];       // 4 KB  g2s[i] = g(|i-512|)
    __shared__ float part[4][DET];    // 8 KB

    const int a = blockIdx.x >> 1;
    const int z = blockIdx.x & 1;

    for (int i = t; i < 1024; i += 256) {
        int k = i - 512; if (k < 0) k = -k;
        float g = 0.0f;
        if (k == 0)      g = 0.5f;
        else if (k & 1)  { float fk = (float)k; g = -0.20264236728467558f / (fk * fk); }
        g2s[i] = g;
    }
    for (int i = t; i < 4 * DET; i += 256) {
        int b = i >> 9, j = i & 511;
        xcols[b][j] = x[((4 * z + b) * DET + j) * NA + a];
    }
    __syncthreads();

    const int w  = t >> 6, l = t & 63;
    const int d0 = l << 3;

    float acc[8];
#pragma unroll
    for (int r = 0; r < 8; ++r) acc[r] = 0.0f;

    float W[16];
#pragma unroll
    for (int q = 0; q < 4; ++q)
        *(float4*)(W + 4 * q) = *(const float4*)(g2s + 504 + d0 + 4 * q);
    float xv[8];
    *(float4*)(xv)     = *(const float4*)(&xcols[w][0]);
    *(float4*)(xv + 4) = *(const float4*)(&xcols[w][4]);

    for (int j0 = 0; j0 < 512; j0 += 8) {
        float nxv[8], nW[8];
        const bool more = (j0 < 504);
        if (more) {
            *(float4*)(nxv)     = *(const float4*)(&xcols[w][j0 + 8]);
            *(float4*)(nxv + 4) = *(const float4*)(&xcols[w][j0 + 12]);
            *(float4*)(nW)      = *(const float4*)(g2s + 496 + d0 - j0);
            *(float4*)(nW + 4)  = *(const float4*)(g2s + 500 + d0 - j0);
        }
#pragma unroll
        for (int jj = 0; jj < 8; ++jj)
#pragma unroll
            for (int r = 0; r < 8; ++r)
                acc[r] = fmaf(xv[jj], W[8 + r - jj], acc[r]);
        if (more) {
#pragma unroll
            for (int i = 7; i >= 0; --i) W[i + 8] = W[i];
#pragma unroll
            for (int i = 0; i < 8; ++i) { W[i] = nW[i]; xv[i] = nxv[i]; }
        }
    }

    *(float4*)(&part[w][d0])     = *(const float4*)(acc);
    *(float4*)(&part[w][d0 + 4]) = *(const float4*)(acc + 4);
    __syncthreads();

    // tap-pair pack: word b = half2(part[b][i], part[b][i+1]); d=511 pairs with 0
    for (int i = t; i < DET; i += 256) {
        uint4 pk;
        unsigned* pkw = &pk.x;
#pragma unroll
        for (int b = 0; b < 4; ++b) {
            float v0 = part[b][i];
            float v1 = (i < DET - 1) ? part[b][i + 1] : 0.0f;
            __half2 h = __halves2half2(__float2half_rn(v0), __float2half_rn(v1));
            pkw[b] = *(unsigned*)&h;
        }
        xsT2[((size_t)a * DET + i) * 2 + z] = pk;
    }
}

// ---------------- backprojection: 16x8 tiles, 128-thread blocks, 26 waves/CU ----------------
// 2048 blocks, 1 thread = 1 pixel x 8 batches; register-prefetch pipelined staging;
// per pixel-angle: addr math once, 2 ds_read_b128, 8 v_dot2_f32_f16. Plain stores.
__global__ __launch_bounds__(128, 7) void backproj_kernel(const float4* __restrict__ tang,
                                                          const uint4* __restrict__ xs,
                                                          float* __restrict__ out) {
    __shared__ uint4 win[2][CHUNK][WWIN];   // 11.5 KB -> 13 blocks/CU

    const int tile = blockIdx.x;
    const int x0 = (tile & 31) << 4, y0 = (tile >> 5) << 3;
    const int t = threadIdx.x;
    const int px = t & 15, py = t >> 4;     // 16 x 8
    const float xg = (float)(2 * (x0 + px) - 511) * (1.0f / 511.0f);
    const float yg = (float)(2 * (y0 + py) - 511) * (1.0f / 511.0f);

    float acc[8];
#pragma unroll
    for (int j = 0; j < 8; ++j) acc[j] = 0.0f;

    const float4* ta = tang + (size_t)tile * NA;

    uint4 p[NPF];

    // prefetch chunk 0
#pragma unroll
    for (int k = 0; k < NPF; ++k) {
        int i = t + 128 * k;
        p[k] = make_uint4(0u, 0u, 0u, 0u);
        if (i < NITEM) {
            int ci  = i / (WWIN * 2);
            int r   = i - ci * (WWIN * 2);
            int off = r >> 1, gg = r & 1;
            int d   = __float_as_int(ta[ci].w) + off;
            if ((unsigned)d < 512u)
                p[k] = xs[((size_t)ci * DET + d) * 2 + gg];
        }
    }

    for (int c = 0; c < NA / CHUNK; ++c) {
        __syncthreads();   // previous chunk's readers done
        // write prefetched registers to LDS (compiler waits vmcnt here)
#pragma unroll
        for (int k = 0; k < NPF; ++k) {
            int i = t + 128 * k;
            if (i < NITEM) {
                int ci  = i / (WWIN * 2);
                int r   = i - ci * (WWIN * 2);
                int off = r >> 1, gg = r & 1;
                win[gg][ci][off] = p[k];
            }
        }
        __syncthreads();

        // issue next chunk's loads (consumed at next write phase)
        if (c < NA / CHUNK - 1) {
#pragma unroll
            for (int k = 0; k < NPF; ++k) {
                int i = t + 128 * k;
                p[k] = make_uint4(0u, 0u, 0u, 0u);
                if (i < NITEM) {
                    int ci  = i / (WWIN * 2);
                    int r   = i - ci * (WWIN * 2);
                    int off = r >> 1, gg = r & 1;
                    int a   = (c + 1) * CHUNK + ci;
                    int d   = __float_as_int(ta[a].w) + off;
                    if ((unsigned)d < 512u)
                        p[k] = xs[((size_t)a * DET + d) * 2 + gg];
                }
            }
        }

#pragma unroll 6
        for (int ci = 0; ci < CHUNK; ++ci) {
            float4 A = ta[c * CHUNK + ci];             // uniform -> s_load_dwordx4
            float yv = fmaf(xg, A.y, A.x) - yg * A.z;  // window-relative, >= 1
            float fi = floorf(yv);
            int  off = (int)fi;
            float wgt = yv - fi;
            auto pkw = __builtin_amdgcn_cvt_pkrtz(1.0f - wgt, wgt);  // v_cvt_pkrtz_f16_f32
            half2_t wv = *(half2_t*)&pkw;
            uint4 u0 = win[0][ci][off];                // ds_read_b128
            uint4 u1 = win[1][ci][off];                // ds_read_b128, +imm offset
            acc[0] = __builtin_amdgcn_fdot2(*(half2_t*)&u0.x, wv, acc[0], false);
            acc[1] = __builtin_amdgcn_fdot2(*(half2_t*)&u0.y, wv, acc[1], false);
            acc[2] = __builtin_amdgcn_fdot2(*(half2_t*)&u0.z, wv, acc[2], false);
            acc[3] = __builtin_amdgcn_fdot2(*(half2_t*)&u0.w, wv, acc[3], false);
            acc[4] = __builtin_amdgcn_fdot2(*(half2_t*)&u1.x, wv, acc[4], false);
            acc[5] = __builtin_amdgcn_fdot2(*(half2_t*)&u1.y, wv, acc[5], false);
            acc[6] = __builtin_amdgcn_fdot2(*(half2_t*)&u1.z, wv, acc[6], false);
            acc[7] = __builtin_amdgcn_fdot2(*(half2_t*)&u1.w, wv, acc[7], false);
        }
    }

    const float r2 = xg * xg + yg * yg;
    const float m  = (r2 <= 1.0f) ? 0.008726646259971648f : 0.0f;  // pi/360 masked
    const size_t pbase = ((size_t)(y0 + py) << 9) + (size_t)(x0 + px);
#pragma unroll
    for (int j = 0; j < 8; ++j)
        out[((size_t)j << 18) + pbase] = acc[j] * m;
}

extern "C" void kernel_launch(void* const* d_in, const int* in_sizes, int n_in,
                              void* d_out, int out_size, void* d_ws, size_t ws_size,
                              hipStream_t stream) {
    const float* x = (const float*)d_in[0];
    float* out = (float*)d_out;
    float* ws  = (float*)d_ws;

    float4* tang = (float4*)ws;
    uint4*  xsT2 = (uint4*)(ws + TANG_FLOATS);

    const int prep_blocks = (NTILES * NA + 255) / 256;   // 1440
    prep_filter_kernel<<<2 * NA + prep_blocks, 256, 0, stream>>>(x, tang, xsT2);
    backproj_kernel<<<NTILES, 128, 0, stream>>>(tang, xsT2, out);
}

// Round 12
// 127.795 us; speedup vs baseline: 1.1021x; 1.1021x over previous
//
#include <hip/hip_runtime.h>
#include <hip/hip_fp16.h>
#include <math.h>

#define DET 512
#define NA 180
#define NTILES 1024                   // 32 x 32 tiles of 16x16 pixels
#define TANG_FLOATS (NTILES * NA * 4) // 2.95 MB
#define CHUNK 36
#define WWIN 24
#define NITEM (CHUNK * WWIN * 2)      // 1728 uint4 per chunk
#define NPF 7                         // ceil(1728/256)

typedef _Float16 half2_t __attribute__((ext_vector_type(2)));

// ws layout (floats):
//  [0, TANG_FLOATS)  : tang float4 per (tile,angle): {bias=255.5-w0, C, S, w0 int bits}
//  then xsT2         : uint4[NA*DET*2] delta-packed sinogram (2.95 MB):
//                      uint4 (a,d,g) = { half2(s_b[d], s_b[d+1]-s_b[d]) : b = 4g..4g+3 }

// ---------------- fused prep + filter ----------------
// blocks [0, 2*NA): filter (angle = blk>>1, batch-half z = blk&1, 4 batches)
// blocks [2*NA, 2*NA+720): prep of tang
__global__ __launch_bounds__(256) void prep_filter_kernel(const float* __restrict__ x,
                                                          float4* __restrict__ tang,
                                                          uint4* __restrict__ xsT2) {
    const int t = threadIdx.x;
    if (blockIdx.x >= 2 * NA) {
        int idx = (blockIdx.x - 2 * NA) * 256 + t;
        if (idx < NTILES * NA) {
            int tile = idx / NA;
            int a = idx - tile * NA;
            float th = (float)a * 0.017453292519943295f;
            float C = 255.5f * cosf(th);
            float S = 255.5f * sinf(th);
            int x0 = (tile & 31) << 4, y0 = (tile >> 5) << 4;
            float xga = (float)(2 * x0 - 511)        * (1.0f / 511.0f);
            float xgb = (float)(2 * (x0 + 15) - 511) * (1.0f / 511.0f);
            float yga = (float)(2 * y0 - 511)        * (1.0f / 511.0f);
            float ygb = (float)(2 * (y0 + 15) - 511) * (1.0f / 511.0f);
            // min over tile corners of yv = 255.5 + xg*C - yg*S (linear in xg,yg)
            float mn = 255.5f + fminf(xga * C, xgb * C) + fminf(-yga * S, -ygb * S);
            int w0 = (int)floorf(mn) - 1;     // -1 slack for fma rounding differences
            tang[idx] = make_float4(255.5f - (float)w0, C, S, __int_as_float(w0));
        }
        return;
    }

    // ---- filter: one wave = full 512-tap conv of one batch-column ----
    __shared__ float xcols[4][DET];   // 8 KB
    __shared__ float g2s[1024];       // 4 KB  g2s[i] = g(|i-512|)
    __shared__ float part[4][DET];    // 8 KB

    const int a = blockIdx.x >> 1;
    const int z = blockIdx.x & 1;

    for (int i = t; i < 1024; i += 256) {
        int k = i - 512; if (k < 0) k = -k;
        float g = 0.0f;
        if (k == 0)      g = 0.5f;
        else if (k & 1)  { float fk = (float)k; g = -0.20264236728467558f / (fk * fk); }
        g2s[i] = g;
    }
    for (int i = t; i < 4 * DET; i += 256) {
        int b = i >> 9, j = i & 511;
        xcols[b][j] = x[((4 * z + b) * DET + j) * NA + a];
    }
    __syncthreads();

    const int w  = t >> 6, l = t & 63;
    const int d0 = l << 3;

    float acc[8];
#pragma unroll
    for (int r = 0; r < 8; ++r) acc[r] = 0.0f;

    float W[16];
#pragma unroll
    for (int q = 0; q < 4; ++q)
        *(float4*)(W + 4 * q) = *(const float4*)(g2s + 504 + d0 + 4 * q);
    float xv[8];
    *(float4*)(xv)     = *(const float4*)(&xcols[w][0]);
    *(float4*)(xv + 4) = *(const float4*)(&xcols[w][4]);

    for (int j0 = 0; j0 < 512; j0 += 8) {
        float nxv[8], nW[8];
        const bool more = (j0 < 504);
        if (more) {
            *(float4*)(nxv)     = *(const float4*)(&xcols[w][j0 + 8]);
            *(float4*)(nxv + 4) = *(const float4*)(&xcols[w][j0 + 12]);
            *(float4*)(nW)      = *(const float4*)(g2s + 496 + d0 - j0);
            *(float4*)(nW + 4)  = *(const float4*)(g2s + 500 + d0 - j0);
        }
#pragma unroll
        for (int jj = 0; jj < 8; ++jj)
#pragma unroll
            for (int r = 0; r < 8; ++r)
                acc[r] = fmaf(xv[jj], W[8 + r - jj], acc[r]);
        if (more) {
#pragma unroll
            for (int i = 7; i >= 0; --i) W[i + 8] = W[i];
#pragma unroll
            for (int i = 0; i < 8; ++i) { W[i] = nW[i]; xv[i] = nxv[i]; }
        }
    }

    *(float4*)(&part[w][d0])     = *(const float4*)(acc);
    *(float4*)(&part[w][d0 + 4]) = *(const float4*)(acc + 4);
    __syncthreads();

    // delta pack: word b = half2(v0, v1-v0); d=511 pairs with v1=0 -> dv=-v0
    for (int i = t; i < DET; i += 256) {
        uint4 pk;
        unsigned* pkw = &pk.x;
#pragma unroll
        for (int b = 0; b < 4; ++b) {
            float v0 = part[b][i];
            float v1 = (i < DET - 1) ? part[b][i + 1] : 0.0f;
            __half2 h = __halves2half2(__float2half_rn(v0), __float2half_rn(v1 - v0));
            pkw[b] = *(unsigned*)&h;
        }
        xsT2[((size_t)a * DET + i) * 2 + z] = pk;
    }
}

// ---------------- backprojection: register-prefetch pipelined staging ----------------
// 1024 blocks (16x16 tile each), 1 thread = 1 pixel x 8 batches.
// Per pixel-angle: addr math once, 2 ds_read_b128, 8 v_dot2_f32_f16 with (1,w) weights.
__global__ __launch_bounds__(256, 4) void backproj_kernel(const float4* __restrict__ tang,
                                                          const uint4* __restrict__ xs,
                                                          float* __restrict__ out) {
    __shared__ uint4 win[2][CHUNK][WWIN];   // 27.6 KB -> 4 blocks/CU

    const int tile = blockIdx.x;
    const int x0 = (tile & 31) << 4, y0 = (tile >> 5) << 4;
    const int t = threadIdx.x;
    const int px = t & 15, py = t >> 4;
    const float xg = (float)(2 * (x0 + px) - 511) * (1.0f / 511.0f);
    const float yg = (float)(2 * (y0 + py) - 511) * (1.0f / 511.0f);

    float acc[8];
#pragma unroll
    for (int j = 0; j < 8; ++j) acc[j] = 0.0f;

    const float4* ta = tang + (size_t)tile * NA;

    uint4 p[NPF];

    // prefetch chunk 0
#pragma unroll
    for (int k = 0; k < NPF; ++k) {
        int i = t + 256 * k;
        p[k] = make_uint4(0u, 0u, 0u, 0u);
        if (i < NITEM) {
            int ci  = i / (WWIN * 2);
            int r   = i - ci * (WWIN * 2);
            int off = r >> 1, gg = r & 1;
            int d   = __float_as_int(ta[ci].w) + off;
            if ((unsigned)d < 512u)
                p[k] = xs[((size_t)ci * DET + d) * 2 + gg];
        }
    }

    for (int c = 0; c < NA / CHUNK; ++c) {
        __syncthreads();   // previous chunk's readers done
        // write prefetched registers to LDS (compiler waits vmcnt here)
#pragma unroll
        for (int k = 0; k < NPF; ++k) {
            int i = t + 256 * k;
            if (i < NITEM) {
                int ci  = i / (WWIN * 2);
                int r   = i - ci * (WWIN * 2);
                int off = r >> 1, gg = r & 1;
                win[gg][ci][off] = p[k];
            }
        }
        __syncthreads();

        // issue next chunk's loads (consumed at next write phase)
        if (c < NA / CHUNK - 1) {
#pragma unroll
            for (int k = 0; k < NPF; ++k) {
                int i = t + 256 * k;
                p[k] = make_uint4(0u, 0u, 0u, 0u);
                if (i < NITEM) {
                    int ci  = i / (WWIN * 2);
                    int r   = i - ci * (WWIN * 2);
                    int off = r >> 1, gg = r & 1;
                    int a   = (c + 1) * CHUNK + ci;
                    int d   = __float_as_int(ta[a].w) + off;
                    if ((unsigned)d < 512u)
                        p[k] = xs[((size_t)a * DET + d) * 2 + gg];
                }
            }
        }

#pragma unroll 6
        for (int ci = 0; ci < CHUNK; ++ci) {
            float4 A = ta[c * CHUNK + ci];             // uniform -> s_load_dwordx4
            float yv = fmaf(xg, A.y, A.x) - yg * A.z;  // window-relative, >= 1
            float fi = floorf(yv);
            int  off = (int)fi;
            float wgt = yv - fi;
            auto pkw = __builtin_amdgcn_cvt_pkrtz(1.0f, wgt);   // (1, w) weights
            half2_t wv = *(half2_t*)&pkw;
            uint4 u0 = win[0][ci][off];                // ds_read_b128
            uint4 u1 = win[1][ci][off];                // ds_read_b128, +imm offset
            acc[0] = __builtin_amdgcn_fdot2(*(half2_t*)&u0.x, wv, acc[0], false);
            acc[1] = __builtin_amdgcn_fdot2(*(half2_t*)&u0.y, wv, acc[1], false);
            acc[2] = __builtin_amdgcn_fdot2(*(half2_t*)&u0.z, wv, acc[2], false);
            acc[3] = __builtin_amdgcn_fdot2(*(half2_t*)&u0.w, wv, acc[3], false);
            acc[4] = __builtin_amdgcn_fdot2(*(half2_t*)&u1.x, wv, acc[4], false);
            acc[5] = __builtin_amdgcn_fdot2(*(half2_t*)&u1.y, wv, acc[5], false);
            acc[6] = __builtin_amdgcn_fdot2(*(half2_t*)&u1.z, wv, acc[6], false);
            acc[7] = __builtin_amdgcn_fdot2(*(half2_t*)&u1.w, wv, acc[7], false);
        }
    }

    const float r2 = xg * xg + yg * yg;
    const float m  = (r2 <= 1.0f) ? 0.008726646259971648f : 0.0f;  // pi/360 masked
    const size_t pbase = ((size_t)(y0 + py) << 9) + (size_t)(x0 + px);
#pragma unroll
    for (int j = 0; j < 8; ++j)
        out[((size_t)j << 18) + pbase] = acc[j] * m;
}

extern "C" void kernel_launch(void* const* d_in, const int* in_sizes, int n_in,
                              void* d_out, int out_size, void* d_ws, size_t ws_size,
                              hipStream_t stream) {
    const float* x = (const float*)d_in[0];
    float* out = (float*)d_out;
    float* ws  = (float*)d_ws;

    float4* tang = (float4*)ws;
    uint4*  xsT2 = (uint4*)(ws + TANG_FLOATS);

    const int prep_blocks = (NTILES * NA + 255) / 256;   // 720
    prep_filter_kernel<<<2 * NA + prep_blocks, 256, 0, stream>>>(x, tang, xsT2);
    backproj_kernel<<<NTILES, 256, 0, stream>>>(tang, xsT2, out);
}

// Round 13
// 120.751 us; speedup vs baseline: 1.1663x; 1.0583x over previous
//
#include <hip/hip_runtime.h>
#include <hip/hip_fp16.h>
#include <math.h>

#define DET 512
#define NA 180
#define NTILES 1024                   // 32 x 32 tiles of 16x16 pixels
#define TANG_FLOATS (NTILES * NA * 4) // 2.95 MB
#define CHUNK 18
#define WWIN 24
#define NCH 5                         // chunks per half (90 angles)
#define NITEM (CHUNK * WWIN * 2)      // 864 uint4 per chunk
#define NPF 4                         // ceil(864/256)

typedef _Float16 half2_t __attribute__((ext_vector_type(2)));

// ws layout (floats):
//  [0, TANG_FLOATS)  : tang float4 per (tile,angle): {bias=255.5-w0, C, S, w0 int bits}
//  then xsT2         : uint4[NA*DET*2] delta-packed sinogram (2.95 MB):
//                      uint4 (a,d,g) = { half2(s_b[d], s_b[d+1]-s_b[d]) : b = 4g..4g+3 }

// ---------------- fused prep + filter + out-zero ----------------
// blocks [0, 4*NA): filter (angle = blk>>2, batch-pair z = blk&3; wave w: local batch w>>1,
//                   j-half w&1; partials reduced through LDS)
// blocks [4*NA, 4*NA+720): prep of tang + zero d_out (no extra graph node)
__global__ __launch_bounds__(256) void prep_filter_kernel(const float* __restrict__ x,
                                                          float4* __restrict__ tang,
                                                          unsigned* __restrict__ xsT2,
                                                          float4* __restrict__ out4) {
    const int t = threadIdx.x;
    if (blockIdx.x >= 4 * NA) {
        const int pb = blockIdx.x - 4 * NA;
        int idx = pb * 256 + t;
        if (idx < NTILES * NA) {
            int tile = idx / NA;
            int a = idx - tile * NA;
            float th = (float)a * 0.017453292519943295f;
            float C = 255.5f * cosf(th);
            float S = 255.5f * sinf(th);
            int x0 = (tile & 31) << 4, y0 = (tile >> 5) << 4;
            float xga = (float)(2 * x0 - 511)        * (1.0f / 511.0f);
            float xgb = (float)(2 * (x0 + 15) - 511) * (1.0f / 511.0f);
            float yga = (float)(2 * y0 - 511)        * (1.0f / 511.0f);
            float ygb = (float)(2 * (y0 + 15) - 511) * (1.0f / 511.0f);
            // min over tile corners of yv = 255.5 + xg*C - yg*S (linear in xg,yg)
            float mn = 255.5f + fminf(xga * C, xgb * C) + fminf(-yga * S, -ygb * S);
            int w0 = (int)floorf(mn) - 1;     // -1 slack for fma rounding differences
            tang[idx] = make_float4(255.5f - (float)w0, C, S, __int_as_float(w0));
        }
        // zero d_out: 524288 float4 spread over 720 blocks
        for (int q = t; q < 729; q += 256) {
            int o = pb * 729 + q;
            if (o < (1 << 19))
                out4[o] = make_float4(0.0f, 0.0f, 0.0f, 0.0f);
        }
        return;
    }

    // ---- filter: wave w -> local batch lb=w>>1 (global 2z+lb), j-half h=w&1 ----
    __shared__ float xcols[2][DET];   // 4 KB
    __shared__ float g2s[1024];       // 4 KB  g2s[i] = g(|i-512|)
    __shared__ float part[4][DET];    // 8 KB

    const int a = blockIdx.x >> 2;
    const int z = blockIdx.x & 3;

    for (int i = t; i < 1024; i += 256) {
        int k = i - 512; if (k < 0) k = -k;
        float g = 0.0f;
        if (k == 0)      g = 0.5f;
        else if (k & 1)  { float fk = (float)k; g = -0.20264236728467558f / (fk * fk); }
        g2s[i] = g;
    }
    for (int i = t; i < 2 * DET; i += 256) {
        int b = i >> 9, j = i & 511;
        xcols[b][j] = x[((2 * z + b) * DET + j) * NA + a];
    }
    __syncthreads();

    const int w  = t >> 6, l = t & 63;
    const int lb = w >> 1, h = w & 1;
    const int d0 = l << 3;
    const int jstart = h << 8;

    float acc[8];
#pragma unroll
    for (int r = 0; r < 8; ++r) acc[r] = 0.0f;

    // W[i] = g2s[504 + d0 - j0 + i]
    float W[16];
#pragma unroll
    for (int q = 0; q < 4; ++q)
        *(float4*)(W + 4 * q) = *(const float4*)(g2s + 504 + d0 - jstart + 4 * q);
    float xv[8];
    *(float4*)(xv)     = *(const float4*)(&xcols[lb][jstart]);
    *(float4*)(xv + 4) = *(const float4*)(&xcols[lb][jstart + 4]);

    for (int j0 = jstart; j0 < jstart + 256; j0 += 8) {
        float nxv[8], nW[8];
        const bool more = (j0 < jstart + 248);
        if (more) {
            *(float4*)(nxv)     = *(const float4*)(&xcols[lb][j0 + 8]);
            *(float4*)(nxv + 4) = *(const float4*)(&xcols[lb][j0 + 12]);
            *(float4*)(nW)      = *(const float4*)(g2s + 496 + d0 - j0);
            *(float4*)(nW + 4)  = *(const float4*)(g2s + 500 + d0 - j0);
        }
#pragma unroll
        for (int jj = 0; jj < 8; ++jj)
#pragma unroll
            for (int r = 0; r < 8; ++r)
                acc[r] = fmaf(xv[jj], W[8 + r - jj], acc[r]);
        if (more) {
#pragma unroll
            for (int i = 7; i >= 0; --i) W[i + 8] = W[i];
#pragma unroll
            for (int i = 0; i < 8; ++i) { W[i] = nW[i]; xv[i] = nxv[i]; }
        }
    }

    *(float4*)(&part[w][d0])     = *(const float4*)(acc);
    *(float4*)(&part[w][d0 + 4]) = *(const float4*)(acc + 4);
    __syncthreads();

    // reduce j-halves + delta pack: word = half2(v0, v1-v0); d=511 pairs with v1=0
    for (int i = t; i < DET; i += 256) {
        unsigned pw[2];
#pragma unroll
        for (int b = 0; b < 2; ++b) {
            float v0 = part[2 * b][i] + part[2 * b + 1][i];
            float v1 = 0.0f;
            if (i < DET - 1) v1 = part[2 * b][i + 1] + part[2 * b + 1][i + 1];
            __half2 hh = __halves2half2(__float2half_rn(v0), __float2half_rn(v1 - v0));
            pw[b] = *(unsigned*)&hh;
        }
        // uint4 layout: word (a,d,gg)[b4] = batch 4*gg+b4; this block: batches 2z,2z+1
        *(uint2*)(xsT2 + ((size_t)a * DET + i) * 8 + 4 * (z >> 1) + 2 * (z & 1)) =
            make_uint2(pw[0], pw[1]);
    }
}

// ---------------- backprojection: angle-split halves, 8 blocks/CU, atomic epilogue ----------------
// grid 2048: tile = bx & 1023, half = bx >> 10 (angles [90h, 90h+90)).
// 1 thread = 1 pixel x 8 batches; register-prefetch pipelined staging;
// per pixel-angle: addr math once, 2 ds_read_b128, 8 v_dot2_f32_f16 with (1,w) weights.
__global__ __launch_bounds__(256, 8) void backproj_kernel(const float4* __restrict__ tang,
                                                          const uint4* __restrict__ xs,
                                                          float* __restrict__ out) {
    __shared__ uint4 win[2][CHUNK][WWIN];   // 13.8 KB -> 8 blocks/CU

    const int tile = blockIdx.x & 1023;
    const int abase = (blockIdx.x >> 10) * 90;
    const int x0 = (tile & 31) << 4, y0 = (tile >> 5) << 4;
    const int t = threadIdx.x;
    const int px = t & 15, py = t >> 4;
    const float xg = (float)(2 * (x0 + px) - 511) * (1.0f / 511.0f);
    const float yg = (float)(2 * (y0 + py) - 511) * (1.0f / 511.0f);

    float acc[8];
#pragma unroll
    for (int j = 0; j < 8; ++j) acc[j] = 0.0f;

    const float4* ta = tang + (size_t)tile * NA;

    uint4 p[NPF];

    // prefetch chunk 0
#pragma unroll
    for (int k = 0; k < NPF; ++k) {
        int i = t + 256 * k;
        p[k] = make_uint4(0u, 0u, 0u, 0u);
        if (i < NITEM) {
            int ci  = i / (WWIN * 2);
            int r   = i - ci * (WWIN * 2);
            int off = r >> 1, gg = r & 1;
            int a   = abase + ci;
            int d   = __float_as_int(ta[a].w) + off;
            if ((unsigned)d < 512u)
                p[k] = xs[((size_t)a * DET + d) * 2 + gg];
        }
    }

    for (int c = 0; c < NCH; ++c) {
        __syncthreads();   // previous chunk's readers done
        // write prefetched registers to LDS (compiler waits vmcnt here)
#pragma unroll
        for (int k = 0; k < NPF; ++k) {
            int i = t + 256 * k;
            if (i < NITEM) {
                int ci  = i / (WWIN * 2);
                int r   = i - ci * (WWIN * 2);
                int off = r >> 1, gg = r & 1;
                win[gg][ci][off] = p[k];
            }
        }
        __syncthreads();

        // issue next chunk's loads (consumed at next write phase)
        if (c < NCH - 1) {
#pragma unroll
            for (int k = 0; k < NPF; ++k) {
                int i = t + 256 * k;
                p[k] = make_uint4(0u, 0u, 0u, 0u);
                if (i < NITEM) {
                    int ci  = i / (WWIN * 2);
                    int r   = i - ci * (WWIN * 2);
                    int off = r >> 1, gg = r & 1;
                    int a   = abase + (c + 1) * CHUNK + ci;
                    int d   = __float_as_int(ta[a].w) + off;
                    if ((unsigned)d < 512u)
                        p[k] = xs[((size_t)a * DET + d) * 2 + gg];
                }
            }
        }

#pragma unroll 6
        for (int ci = 0; ci < CHUNK; ++ci) {
            float4 A = ta[abase + c * CHUNK + ci];     // uniform -> s_load_dwordx4
            float yv = fmaf(xg, A.y, A.x) - yg * A.z;  // window-relative, >= 1
            float fi = floorf(yv);
            int  off = (int)fi;
            float wgt = yv - fi;
            auto pkw = __builtin_amdgcn_cvt_pkrtz(1.0f, wgt);   // (1, w) weights
            half2_t wv = *(half2_t*)&pkw;
            uint4 u0 = win[0][ci][off];                // ds_read_b128
            uint4 u1 = win[1][ci][off];                // ds_read_b128, +imm offset
            acc[0] = __builtin_amdgcn_fdot2(*(half2_t*)&u0.x, wv, acc[0], false);
            acc[1] = __builtin_amdgcn_fdot2(*(half2_t*)&u0.y, wv, acc[1], false);
            acc[2] = __builtin_amdgcn_fdot2(*(half2_t*)&u0.z, wv, acc[2], false);
            acc[3] = __builtin_amdgcn_fdot2(*(half2_t*)&u0.w, wv, acc[3], false);
            acc[4] = __builtin_amdgcn_fdot2(*(half2_t*)&u1.x, wv, acc[4], false);
            acc[5] = __builtin_amdgcn_fdot2(*(half2_t*)&u1.y, wv, acc[5], false);
            acc[6] = __builtin_amdgcn_fdot2(*(half2_t*)&u1.z, wv, acc[6], false);
            acc[7] = __builtin_amdgcn_fdot2(*(half2_t*)&u1.w, wv, acc[7], false);
        }
    }

    // two halves per address, fp32 add commutative -> deterministic
    const float r2 = xg * xg + yg * yg;
    const float m  = (r2 <= 1.0f) ? 0.008726646259971648f : 0.0f;  // pi/360 masked
    const size_t pbase = ((size_t)(y0 + py) << 9) + (size_t)(x0 + px);
#pragma unroll
    for (int j = 0; j < 8; ++j)
        atomicAdd(&out[((size_t)j << 18) + pbase], acc[j] * m);
}

extern "C" void kernel_launch(void* const* d_in, const int* in_sizes, int n_in,
                              void* d_out, int out_size, void* d_ws, size_t ws_size,
                              hipStream_t stream) {
    const float* x = (const float*)d_in[0];
    float* out = (float*)d_out;
    float* ws  = (float*)d_ws;

    float4*   tang = (float4*)ws;
    unsigned* xsT2 = (unsigned*)(ws + TANG_FLOATS);

    const int prep_blocks = (NTILES * NA + 255) / 256;   // 720
    prep_filter_kernel<<<4 * NA + prep_blocks, 256, 0, stream>>>(x, tang, xsT2, (float4*)out);
    backproj_kernel<<<2 * NTILES, 256, 0, stream>>>(tang, (const uint4*)xsT2, out);
}

// Round 14
// 118.083 us; speedup vs baseline: 1.1927x; 1.0226x over previous
//
#include <hip/hip_runtime.h>
#include <hip/hip_fp16.h>
#include <math.h>

#define DET 512
#define NA 180
#define NTILES 1024                   // 32 x 32 tiles of 16x16 pixels
#define TANG_FLOATS (NTILES * NA * 4) // 2.95 MB
#define CHUNK 10
#define WWIN 24
#define NCH 9                         // chunks per half (90 angles)
#define NSLOT (CHUNK * WWIN * 2)      // 480 uint4 slots per chunk
#define ZERO_IDX (NA * DET * 2)       // zero uint4 slot index in xsT2

typedef _Float16 half2_t __attribute__((ext_vector_type(2)));

// direct global->LDS DMA, 16 B per lane; lds dest = wave-uniform base + lane*16
__device__ __forceinline__ void async_copy16(void* lds, const void* g) {
    __builtin_amdgcn_global_load_lds(
        (const __attribute__((address_space(1))) unsigned*)g,
        (__attribute__((address_space(3))) unsigned*)(unsigned)(unsigned long long)lds,
        16, 0, 0);
}

// ws layout (floats):
//  [0, TANG_FLOATS)  : tang float4 per (tile,angle): {bias=255.5-w0, C, S, w0 int bits}
//  then xsT2         : uint4[NA*DET*2] delta-packed sinogram (2.95 MB):
//                      uint4 (a,d,g) = { half2(s_b[d], s_b[d+1]-s_b[d]) : b = 4g..4g+3 }
//                      + one zero uint4 at ZERO_IDX (OOB staging target)

// ---------------- fused prep + filter + out-zero ----------------
__global__ __launch_bounds__(256) void prep_filter_kernel(const float* __restrict__ x,
                                                          float4* __restrict__ tang,
                                                          unsigned* __restrict__ xsT2,
                                                          float4* __restrict__ out4) {
    const int t = threadIdx.x;
    if (blockIdx.x >= 4 * NA) {
        const int pb = blockIdx.x - 4 * NA;
        int idx = pb * 256 + t;
        if (idx < NTILES * NA) {
            int tile = idx / NA;
            int a = idx - tile * NA;
            float th = (float)a * 0.017453292519943295f;
            float C = 255.5f * cosf(th);
            float S = 255.5f * sinf(th);
            int x0 = (tile & 31) << 4, y0 = (tile >> 5) << 4;
            float xga = (float)(2 * x0 - 511)        * (1.0f / 511.0f);
            float xgb = (float)(2 * (x0 + 15) - 511) * (1.0f / 511.0f);
            float yga = (float)(2 * y0 - 511)        * (1.0f / 511.0f);
            float ygb = (float)(2 * (y0 + 15) - 511) * (1.0f / 511.0f);
            float mn = 255.5f + fminf(xga * C, xgb * C) + fminf(-yga * S, -ygb * S);
            int w0 = (int)floorf(mn) - 1;     // -1 slack for fma rounding differences
            tang[idx] = make_float4(255.5f - (float)w0, C, S, __int_as_float(w0));
        }
        if (pb == 0 && t == 0) {
            uint4* z = (uint4*)xsT2 + ZERO_IDX;
            *z = make_uint4(0u, 0u, 0u, 0u);
        }
        // zero d_out: 524288 float4 spread over 720 blocks
        for (int q = t; q < 729; q += 256) {
            int o = pb * 729 + q;
            if (o < (1 << 19))
                out4[o] = make_float4(0.0f, 0.0f, 0.0f, 0.0f);
        }
        return;
    }

    // ---- filter: wave w -> local batch lb=w>>1 (global 2z+lb), j-half h=w&1 ----
    __shared__ float xcols[2][DET];   // 4 KB
    __shared__ float g2s[1024];       // 4 KB  g2s[i] = g(|i-512|)
    __shared__ float part[4][DET];    // 8 KB

    const int a = blockIdx.x >> 2;
    const int z = blockIdx.x & 3;

    for (int i = t; i < 1024; i += 256) {
        int k = i - 512; if (k < 0) k = -k;
        float g = 0.0f;
        if (k == 0)      g = 0.5f;
        else if (k & 1)  { float fk = (float)k; g = -0.20264236728467558f / (fk * fk); }
        g2s[i] = g;
    }
    for (int i = t; i < 2 * DET; i += 256) {
        int b = i >> 9, j = i & 511;
        xcols[b][j] = x[((2 * z + b) * DET + j) * NA + a];
    }
    __syncthreads();

    const int w  = t >> 6, l = t & 63;
    const int lb = w >> 1, h = w & 1;
    const int d0 = l << 3;
    const int jstart = h << 8;

    float acc[8];
#pragma unroll
    for (int r = 0; r < 8; ++r) acc[r] = 0.0f;

    float W[16];
#pragma unroll
    for (int q = 0; q < 4; ++q)
        *(float4*)(W + 4 * q) = *(const float4*)(g2s + 504 + d0 - jstart + 4 * q);
    float xv[8];
    *(float4*)(xv)     = *(const float4*)(&xcols[lb][jstart]);
    *(float4*)(xv + 4) = *(const float4*)(&xcols[lb][jstart + 4]);

    for (int j0 = jstart; j0 < jstart + 256; j0 += 8) {
        float nxv[8], nW[8];
        const bool more = (j0 < jstart + 248);
        if (more) {
            *(float4*)(nxv)     = *(const float4*)(&xcols[lb][j0 + 8]);
            *(float4*)(nxv + 4) = *(const float4*)(&xcols[lb][j0 + 12]);
            *(float4*)(nW)      = *(const float4*)(g2s + 496 + d0 - j0);
            *(float4*)(nW + 4)  = *(const float4*)(g2s + 500 + d0 - j0);
        }
#pragma unroll
        for (int jj = 0; jj < 8; ++jj)
#pragma unroll
            for (int r = 0; r < 8; ++r)
                acc[r] = fmaf(xv[jj], W[8 + r - jj], acc[r]);
        if (more) {
#pragma unroll
            for (int i = 7; i >= 0; --i) W[i + 8] = W[i];
#pragma unroll
            for (int i = 0; i < 8; ++i) { W[i] = nW[i]; xv[i] = nxv[i]; }
        }
    }

    *(float4*)(&part[w][d0])     = *(const float4*)(acc);
    *(float4*)(&part[w][d0 + 4]) = *(const float4*)(acc + 4);
    __syncthreads();

    // reduce j-halves + delta pack: word = half2(v0, v1-v0); d=511 pairs with v1=0
    for (int i = t; i < DET; i += 256) {
        unsigned pw[2];
#pragma unroll
        for (int b = 0; b < 2; ++b) {
            float v0 = part[2 * b][i] + part[2 * b + 1][i];
            float v1 = 0.0f;
            if (i < DET - 1) v1 = part[2 * b][i + 1] + part[2 * b + 1][i + 1];
            __half2 hh = __halves2half2(__float2half_rn(v0), __float2half_rn(v1 - v0));
            pw[b] = *(unsigned*)&hh;
        }
        *(uint2*)(xsT2 + ((size_t)a * DET + i) * 8 + 4 * (z >> 1) + 2 * (z & 1)) =
            make_uint2(pw[0], pw[1]);
    }
}

// ---------------- backprojection: DMA double-buffered staging, 1 barrier/chunk ----------------
// grid 2048: tile = bx & 1023, half = bx >> 10 (angles [90h, 90h+90)).
// 1 thread = 1 pixel x 8 batches; staging via global_load_lds (no VGPR round trip,
// no ds_write); buffer for chunk c+1 filled while computing chunk c.
__global__ __launch_bounds__(256, 8) void backproj_kernel(const float4* __restrict__ tang,
                                                          const uint4* __restrict__ xs,
                                                          float* __restrict__ out) {
    __shared__ uint4 win[2][NSLOT];   // 15.36 KB -> 8 blocks/CU

    const int tile = blockIdx.x & 1023;
    const int abase = (blockIdx.x >> 10) * 90;
    const int x0 = (tile & 31) << 4, y0 = (tile >> 5) << 4;
    const int t = threadIdx.x;
    const int px = t & 15, py = t >> 4;
    const float xg = (float)(2 * (x0 + px) - 511) * (1.0f / 511.0f);
    const float yg = (float)(2 * (y0 + py) - 511) * (1.0f / 511.0f);

    float acc[8];
#pragma unroll
    for (int j = 0; j < 8; ++j) acc[j] = 0.0f;

    const float4* ta = tang + (size_t)tile * NA;
    const uint4*  zs = xs + ZERO_IDX;

    // slot s (of 480): gg = s/240, ci = (s%240)/24, off = s%24
#define STAGE(CC, BB)                                                          \
    {                                                                          \
        int cc = (CC), bb = (BB);                                              \
        _Pragma("unroll")                                                      \
        for (int s0 = 0; s0 < NSLOT; s0 += 256) {                              \
            int s = s0 + t;                                                    \
            if (s < NSLOT) {                                                   \
                int gg  = (s >= CHUNK * WWIN) ? 1 : 0;                         \
                int r   = s - gg * (CHUNK * WWIN);                             \
                int ci  = r / WWIN;                                            \
                int off = r - ci * WWIN;                                       \
                int a   = abase + cc * CHUNK + ci;                             \
                int d   = __float_as_int(ta[a].w) + off;                       \
                const uint4* src = ((unsigned)d < 512u)                        \
                    ? &xs[((size_t)a * DET + d) * 2 + gg] : zs;                \
                async_copy16(&win[bb][s0 + (t & 192)], src);                   \
            }                                                                  \
        }                                                                      \
    }

    STAGE(0, 0);   // preloop: chunk 0 -> buffer 0

    for (int c = 0; c < NCH; ++c) {
        __syncthreads();   // drains DMA for buf[c&1]; prior chunk's readers done
        if (c + 1 < NCH)
            STAGE(c + 1, (c + 1) & 1);   // fills other buffer while we compute

        const uint4* base = &win[c & 1][0];
#pragma unroll
        for (int ci = 0; ci < CHUNK; ++ci) {
            float4 A = ta[abase + c * CHUNK + ci];     // uniform -> s_load_dwordx4
            float yv = fmaf(xg, A.y, A.x) - yg * A.z;  // window-relative, >= 1
            float fi = floorf(yv);
            int  off = (int)fi;
            float wgt = yv - fi;
            auto pkw = __builtin_amdgcn_cvt_pkrtz(1.0f, wgt);   // (1, w) weights
            half2_t wv = *(half2_t*)&pkw;
            uint4 u0 = base[ci * WWIN + off];                  // ds_read_b128
            uint4 u1 = base[CHUNK * WWIN + ci * WWIN + off];   // ds_read_b128, +3840B imm
            acc[0] = __builtin_amdgcn_fdot2(*(half2_t*)&u0.x, wv, acc[0], false);
            acc[1] = __builtin_amdgcn_fdot2(*(half2_t*)&u0.y, wv, acc[1], false);
            acc[2] = __builtin_amdgcn_fdot2(*(half2_t*)&u0.z, wv, acc[2], false);
            acc[3] = __builtin_amdgcn_fdot2(*(half2_t*)&u0.w, wv, acc[3], false);
            acc[4] = __builtin_amdgcn_fdot2(*(half2_t*)&u1.x, wv, acc[4], false);
            acc[5] = __builtin_amdgcn_fdot2(*(half2_t*)&u1.y, wv, acc[5], false);
            acc[6] = __builtin_amdgcn_fdot2(*(half2_t*)&u1.z, wv, acc[6], false);
            acc[7] = __builtin_amdgcn_fdot2(*(half2_t*)&u1.w, wv, acc[7], false);
        }
    }

    // two halves per address, fp32 add commutative -> deterministic
    const float r2 = xg * xg + yg * yg;
    const float m  = (r2 <= 1.0f) ? 0.008726646259971648f : 0.0f;  // pi/360 masked
    const size_t pbase = ((size_t)(y0 + py) << 9) + (size_t)(x0 + px);
#pragma unroll
    for (int j = 0; j < 8; ++j)
        atomicAdd(&out[((size_t)j << 18) + pbase], acc[j] * m);
}

extern "C" void kernel_launch(void* const* d_in, const int* in_sizes, int n_in,
                              void* d_out, int out_size, void* d_ws, size_t ws_size,
                              hipStream_t stream) {
    const float* x = (const float*)d_in[0];
    float* out = (float*)d_out;
    float* ws  = (float*)d_ws;

    float4*   tang = (float4*)ws;
    unsigned* xsT2 = (unsigned*)(ws + TANG_FLOATS);

    const int prep_blocks = (NTILES * NA + 255) / 256;   // 720
    prep_filter_kernel<<<4 * NA + prep_blocks, 256, 0, stream>>>(x, tang, xsT2, (float4*)out);
    backproj_kernel<<<2 * NTILES, 256, 0, stream>>>(tang, (const uint4*)xsT2, out);
}